// Round 8
// baseline (70.174 us; speedup 1.0000x reference)
//
#include <hip/hip_runtime.h>
#include <stdint.h>

#define OUT_F 8192
#define IN_F  8192
#define NGRP  1048576            // OUT*IN/GS
#define BATCH 64
#define KC    16                 // split-K chunks
#define KCHUNK (IN_F / KC)       // 512 k per wave
#define NSTEP (KCHUNK / 32)      // 16 steps of k=32

typedef float f32x4 __attribute__((ext_vector_type(4)));
typedef _Float16 half8_t __attribute__((ext_vector_type(8)));

static __device__ __forceinline__ unsigned int pk_fma_f16(unsigned int a, unsigned int b, unsigned int c) {
  unsigned int d;
  asm("v_pk_fma_f16 %0, %1, %2, %3" : "=v"(d) : "v"(a), "v"(b), "v"(c));
  return d;
}
static __device__ __forceinline__ unsigned int pk16(float a, float b) {
  unsigned short ua = __builtin_bit_cast(unsigned short, (_Float16)a);
  unsigned short ub = __builtin_bit_cast(unsigned short, (_Float16)b);
  return (unsigned int)ua | ((unsigned int)ub << 16);
}

// ---- fused pre-pass: x fp32->f16  +  per-2-group {f16x2(s), f16x2(-(64+z)s)} ----
__global__ __launch_bounds__(256) void pre_kernel(const float* __restrict__ x, ushort* __restrict__ xh,
                                                  const float* __restrict__ scale, const float* __restrict__ zero,
                                                  uint32_t* __restrict__ szb) {
  const int b = blockIdx.x;
  if (b < 512) {                      // 512*256 = BATCH*IN_F/4
    const int i = b * 256 + threadIdx.x;
    float4 v = ((const float4*)x)[i];
    ushort4 o;
    o.x = __builtin_bit_cast(unsigned short, (_Float16)v.x);
    o.y = __builtin_bit_cast(unsigned short, (_Float16)v.y);
    o.z = __builtin_bit_cast(unsigned short, (_Float16)v.z);
    o.w = __builtin_bit_cast(unsigned short, (_Float16)v.w);
    ((ushort4*)xh)[i] = o;
  } else {                            // 1024*256 = NGRP/4
    const int i = (b - 512) * 256 + threadIdx.x;
    float4 s = ((const float4*)scale)[i];
    float4 z = ((const float4*)zero)[i];
    uint4 o;
    o.x = pk16(s.x, s.y);
    o.y = pk16(-(64.f + z.x) * s.x, -(64.f + z.y) * s.y);
    o.z = pk16(s.z, s.w);
    o.w = pk16(-(64.f + z.z) * s.z, -(64.f + z.w) * s.w);
    ((uint4*)szb)[i] = o;
  }
}

// ---- main fused dequant + GEMM: barrier-free, LDS-free, per-wave register dataflow ----
// grid 1024 = 128 c (bid>>3) x 8 kp (bid&7). Wave wid: gq = wid&1, kc = kp*2 + (wid>>1).
// Lane holds its own MFMA B-fragment: n = lane&15 -> Wq row gq*16+n; k-octet = lane>>4.
// Hi nibble -> outputs (gq*16+n)*128+c ; lo nibble -> +4096. All 64 m per wave (4 MFMA/nib).
__global__ __launch_bounds__(256, 4) void hqq_gemm_kernel(
    const int* __restrict__ Wq, const uint32_t* __restrict__ szb,
    const ushort* __restrict__ xh, float* __restrict__ part)
{
  const int t    = threadIdx.x;
  const int bid  = blockIdx.x;
  const int kp   = bid & 7;
  const int c    = bid >> 3;
  const int wid  = t >> 6;
  const int lane = t & 63;
  const int gq   = wid & 1;
  const int kc   = kp * 2 + (wid >> 1);
  const int tr   = lane & 15;
  const int ko   = (lane >> 4) * 8;
  const int kbase = kc * KCHUNK;

  const int* __restrict__ wql =
      Wq + (size_t)(gq * 16 + tr) * NGRP + (size_t)c * IN_F + kbase + ko;
  const uint8_t* __restrict__ szl =
      (const uint8_t*)szb + ((size_t)c * IN_F + kbase + ko) * 4;
  const ushort* __restrict__ xl = xh + (size_t)tr * IN_F + kbase + ko;

  f32x4 acc[2][4];
  #pragma unroll
  for (int n = 0; n < 2; ++n)
    #pragma unroll
    for (int m = 0; m < 4; ++m) acc[n][m] = (f32x4){0.f, 0.f, 0.f, 0.f};

  int4    wr[3][2];    // W prefetch ring, depth 3
  uint4   sr[2][2];    // sz ring, depth 2
  half8_t ar[2][4];    // A ring, depth 2 (L2-resident)

#define LDW(set, s)  do {                                             \
    wr[set][0] = *(const int4*)(wql + (size_t)(s) * 32);              \
    wr[set][1] = *(const int4*)(wql + (size_t)(s) * 32 + 4);          \
  } while (0)
#define LDSZ(set, s) do {                                             \
    sr[set][0] = *(const uint4*)(szl + (size_t)(s) * 128);            \
    sr[set][1] = *(const uint4*)(szl + (size_t)(s) * 128 + 16);       \
  } while (0)
#define LDA(set, s)  do { _Pragma("unroll")                           \
    for (int mq = 0; mq < 4; ++mq)                                    \
      ar[set][mq] = *(const half8_t*)(xl + (size_t)mq * (16 * IN_F) + (s) * 32); \
  } while (0)

  // prologue: 3 W-steps, 2 sz/A-steps in flight
  LDW(0, 0); LDSZ(0, 0); LDA(0, 0);
  LDW(1, 1); LDSZ(1, 1); LDA(1, 1);
  LDW(2, 2);

  #pragma unroll
  for (int s = 0; s < NSTEP; ++s) {
    const int p = s & 1;
    const int q = s % 3;

    // dequant lane's 8 ints -> hi/lo B-fragments (f16 magic: 0x5400|(v<<4) == 64+v)
    union { uint4 u; half8_t h; } uh, ul;
    {
      unsigned tt = ((unsigned)wr[q][0].y << 16) | (unsigned)wr[q][0].x;
      uh.u.x = pk_fma_f16((tt & 0x00F000F0u) | 0x54005400u, sr[p][0].x, sr[p][0].y);
      ul.u.x = pk_fma_f16(((tt << 4) & 0x00F000F0u) | 0x54005400u, sr[p][0].x, sr[p][0].y);
    }
    {
      unsigned tt = ((unsigned)wr[q][0].w << 16) | (unsigned)wr[q][0].z;
      uh.u.y = pk_fma_f16((tt & 0x00F000F0u) | 0x54005400u, sr[p][0].z, sr[p][0].w);
      ul.u.y = pk_fma_f16(((tt << 4) & 0x00F000F0u) | 0x54005400u, sr[p][0].z, sr[p][0].w);
    }
    {
      unsigned tt = ((unsigned)wr[q][1].y << 16) | (unsigned)wr[q][1].x;
      uh.u.z = pk_fma_f16((tt & 0x00F000F0u) | 0x54005400u, sr[p][1].x, sr[p][1].y);
      ul.u.z = pk_fma_f16(((tt << 4) & 0x00F000F0u) | 0x54005400u, sr[p][1].x, sr[p][1].y);
    }
    {
      unsigned tt = ((unsigned)wr[q][1].w << 16) | (unsigned)wr[q][1].z;
      uh.u.w = pk_fma_f16((tt & 0x00F000F0u) | 0x54005400u, sr[p][1].z, sr[p][1].w);
      ul.u.w = pk_fma_f16(((tt << 4) & 0x00F000F0u) | 0x54005400u, sr[p][1].z, sr[p][1].w);
    }
    const half8_t bhi = uh.h;
    const half8_t blo = ul.h;

    // refill consumed W/sz slots early (issue before MFMA block)
    if (s + 3 < NSTEP) LDW(q, s + 3);
    if (s + 2 < NSTEP) LDSZ(p, s + 2);

    #pragma unroll
    for (int mq = 0; mq < 4; ++mq) {
      acc[0][mq] = __builtin_amdgcn_mfma_f32_16x16x32_f16(ar[p][mq], bhi, acc[0][mq], 0, 0, 0);
      acc[1][mq] = __builtin_amdgcn_mfma_f32_16x16x32_f16(ar[p][mq], blo, acc[1][mq], 0, 0, 0);
    }

    // refill A slot after its last MFMA use
    if (s + 2 < NSTEP) LDA(p, s + 2);
  }
#undef LDW
#undef LDSZ
#undef LDA

  // epilogue: C/D col = lane&15 -> o-row, row = (lane>>4)*4 + j -> m
  const int o_hi = (gq * 16 + tr) * 128 + c;
  const int msub = (lane >> 4) * 4;
  float* p0 = part + ((size_t)kc * OUT_F + o_hi) * BATCH + msub;
  float* p1 = part + ((size_t)kc * OUT_F + o_hi + 4096) * BATCH + msub;
  #pragma unroll
  for (int mq = 0; mq < 4; ++mq) {
    *(float4*)(p0 + mq * 16) = (float4){acc[0][mq][0], acc[0][mq][1], acc[0][mq][2], acc[0][mq][3]};
    *(float4*)(p1 + mq * 16) = (float4){acc[1][mq][0], acc[1][mq][1], acc[1][mq][2], acc[1][mq][3]};
  }
}

// ---- split-K reduce + bias + transpose to out[m][o] ----
__global__ __launch_bounds__(256) void reduce_kernel(const float* __restrict__ part,
                                                     const float* __restrict__ bias,
                                                     float* __restrict__ out)
{
  __shared__ float tile[32][65];
  const int ob = blockIdx.x;          // o-range [ob*32, +32)
  const int t  = threadIdx.x;
  {
    const int ol = t >> 3;            // 0..31
    const int mg = t & 7;             // m-octet
    const int o  = ob * 32 + ol;
    const size_t base = (size_t)o * BATCH + mg * 8;
    float s[8] = {0, 0, 0, 0, 0, 0, 0, 0};
    #pragma unroll
    for (int kc = 0; kc < KC; ++kc) {
      const float* p = part + (size_t)kc * OUT_F * BATCH + base;
      float4 a = *(const float4*)p;
      float4 b = *(const float4*)(p + 4);
      s[0] += a.x; s[1] += a.y; s[2] += a.z; s[3] += a.w;
      s[4] += b.x; s[5] += b.y; s[6] += b.z; s[7] += b.w;
    }
    const float bv = bias[o];
    #pragma unroll
    for (int j = 0; j < 8; ++j) tile[ol][mg * 8 + j] = s[j] + bv;
  }
  __syncthreads();
  {
    const int m  = t >> 2;            // 0..63
    const int og = (t & 3) * 8;       // 0..31
    float r[8];
    #pragma unroll
    for (int j = 0; j < 8; ++j) r[j] = tile[og + j][m];
    float* op = out + (size_t)m * OUT_F + ob * 32 + og;
    *(float4*)op       = (float4){r[0], r[1], r[2], r[3]};
    *(float4*)(op + 4) = (float4){r[4], r[5], r[6], r[7]};
  }
}

// ---- correctness fallback (tiny ws), fp32 ----
__global__ void hqq_fallback_kernel(const float* __restrict__ x, const int* __restrict__ Wq,
                                    const float* __restrict__ scale, const float* __restrict__ zero,
                                    const float* __restrict__ bias, float* __restrict__ out)
{
  int idx = blockIdx.x * blockDim.x + threadIdx.x;
  int b = idx >> 13;
  int o = idx & 8191;
  int g = o >> 7, cc = o & 127;
  int r = g & 31;
  bool hi = (g < 32);
  const int*   wrow = Wq    + (size_t)r  * NGRP + (size_t)cc * IN_F;
  const float* srow = scale + (size_t)cc * IN_F;
  const float* zrow = zero  + (size_t)cc * IN_F;
  const float* xrow = x     + (size_t)b  * IN_F;
  float acc = 0.f;
  for (int k = 0; k < IN_F; ++k) {
    int v = wrow[k];
    float nib = (float)(hi ? (v >> 4) : (v & 15));
    acc += xrow[k] * ((nib - zrow[k]) * srow[k]);
  }
  out[idx] = acc + bias[o];
}

extern "C" void kernel_launch(void* const* d_in, const int* in_sizes, int n_in,
                              void* d_out, int out_size, void* d_ws, size_t ws_size,
                              hipStream_t stream) {
  const float* x     = (const float*)d_in[0];
  const int*   Wq    = (const int*)d_in[1];
  const float* scale = (const float*)d_in[2];
  const float* zero  = (const float*)d_in[3];
  const float* bias  = (const float*)d_in[4];
  float* out = (float*)d_out;

  const size_t xh_bytes   = (size_t)BATCH * IN_F * sizeof(ushort);        // 1 MB
  const size_t sz_bytes   = (size_t)NGRP * 4;                             // 4 MB
  const size_t part_bytes = (size_t)KC * BATCH * OUT_F * sizeof(float);   // 32 MB

  if (ws_size >= xh_bytes + sz_bytes + part_bytes) {
    ushort*   xh   = (ushort*)d_ws;
    uint32_t* szb  = (uint32_t*)((char*)d_ws + xh_bytes);
    float*    part = (float*)((char*)d_ws + xh_bytes + sz_bytes);
    pre_kernel<<<1536, 256, 0, stream>>>(x, xh, scale, zero, szb);
    hqq_gemm_kernel<<<128 * 8, 256, 0, stream>>>(Wq, szb, xh, part);
    reduce_kernel<<<OUT_F / 32, 256, 0, stream>>>(part, bias, out);
  } else {
    hqq_fallback_kernel<<<(BATCH * OUT_F) / 256, 256, 0, stream>>>(x, Wq, scale, zero, bias, out);
  }
}